// Round 1
// baseline (3420.629 us; speedup 1.0000x reference)
//
#include <hip/hip_runtime.h>
#include <hip/hip_bf16.h>
#include <cstddef>

#define BB 2
#define TT 2048
#define CC 1024
#define NH 16
#define HD 64
#define NQKV (3*CC)   // 3072

// ---------------- GEMM 1: qkv = x @ w_qkv + b_qkv, scatter to Q/K/V [B,H,T,D] ----------------
__global__ __launch_bounds__(256) void qkv_gemm(const float* __restrict__ X,
                                                const float* __restrict__ W,
                                                const float* __restrict__ bias,
                                                float* __restrict__ Qo,
                                                float* __restrict__ Ko,
                                                float* __restrict__ Vo) {
    __shared__ float As[16][64];   // As[k][m]
    __shared__ float Bs[16][64];   // Bs[k][n]
    const int tid = threadIdx.x;
    const int row0 = blockIdx.y * 64;
    const int col0 = blockIdx.x * 64;
    const int tx = tid & 15, ty = tid >> 4;
    const int lm = tid >> 2, lk = (tid & 3) << 2;   // A tile load coords
    const int bk = tid >> 4, bn = (tid & 15) << 2;  // B tile load coords
    float acc[4][4] = {};
    for (int k0 = 0; k0 < CC; k0 += 16) {
        float4 a4 = *reinterpret_cast<const float4*>(X + (size_t)(row0 + lm) * CC + k0 + lk);
        As[lk + 0][lm] = a4.x; As[lk + 1][lm] = a4.y;
        As[lk + 2][lm] = a4.z; As[lk + 3][lm] = a4.w;
        *reinterpret_cast<float4*>(&Bs[bk][bn]) =
            *reinterpret_cast<const float4*>(W + (size_t)(k0 + bk) * NQKV + col0 + bn);
        __syncthreads();
#pragma unroll
        for (int kk = 0; kk < 16; ++kk) {
            float4 a = *reinterpret_cast<const float4*>(&As[kk][ty * 4]);
            float4 b = *reinterpret_cast<const float4*>(&Bs[kk][tx * 4]);
            float av[4] = {a.x, a.y, a.z, a.w};
            float bv[4] = {b.x, b.y, b.z, b.w};
#pragma unroll
            for (int i = 0; i < 4; ++i)
#pragma unroll
                for (int j = 0; j < 4; ++j)
                    acc[i][j] = fmaf(av[i], bv[j], acc[i][j]);
        }
        __syncthreads();
    }
#pragma unroll
    for (int i = 0; i < 4; ++i) {
        const int m = row0 + ty * 4 + i;
        const int b_ = m >> 11, t = m & (TT - 1);
#pragma unroll
        for (int j = 0; j < 4; ++j) {
            const int n = col0 + tx * 4 + j;
            const float v = acc[i][j] + bias[n];
            const int which = n >> 10;         // 0=q 1=k 2=v
            const int c = n & (CC - 1);
            const int h = c >> 6, d = c & 63;
            const size_t idx = (((size_t)(b_ * NH + h)) * TT + t) * HD + d;
            float* dst = which == 0 ? Qo : (which == 1 ? Ko : Vo);
            dst[idx] = v;
        }
    }
}

// ---------------- GEMM 2: o = attn_out @ w_o + b_o ----------------
__global__ __launch_bounds__(256) void out_gemm(const float* __restrict__ X,
                                                const float* __restrict__ W,
                                                const float* __restrict__ bias,
                                                float* __restrict__ O) {
    __shared__ float As[16][64];
    __shared__ float Bs[16][64];
    const int tid = threadIdx.x;
    const int row0 = blockIdx.y * 64;
    const int col0 = blockIdx.x * 64;
    const int tx = tid & 15, ty = tid >> 4;
    const int lm = tid >> 2, lk = (tid & 3) << 2;
    const int bk = tid >> 4, bn = (tid & 15) << 2;
    float acc[4][4] = {};
    for (int k0 = 0; k0 < CC; k0 += 16) {
        float4 a4 = *reinterpret_cast<const float4*>(X + (size_t)(row0 + lm) * CC + k0 + lk);
        As[lk + 0][lm] = a4.x; As[lk + 1][lm] = a4.y;
        As[lk + 2][lm] = a4.z; As[lk + 3][lm] = a4.w;
        *reinterpret_cast<float4*>(&Bs[bk][bn]) =
            *reinterpret_cast<const float4*>(W + (size_t)(k0 + bk) * CC + col0 + bn);
        __syncthreads();
#pragma unroll
        for (int kk = 0; kk < 16; ++kk) {
            float4 a = *reinterpret_cast<const float4*>(&As[kk][ty * 4]);
            float4 b = *reinterpret_cast<const float4*>(&Bs[kk][tx * 4]);
            float av[4] = {a.x, a.y, a.z, a.w};
            float bv[4] = {b.x, b.y, b.z, b.w};
#pragma unroll
            for (int i = 0; i < 4; ++i)
#pragma unroll
                for (int j = 0; j < 4; ++j)
                    acc[i][j] = fmaf(av[i], bv[j], acc[i][j]);
        }
        __syncthreads();
    }
#pragma unroll
    for (int i = 0; i < 4; ++i) {
        const int m = row0 + ty * 4 + i;
#pragma unroll
        for (int j = 0; j < 4; ++j) {
            const int n = col0 + tx * 4 + j;
            O[(size_t)m * CC + n] = acc[i][j] + bias[n];
        }
    }
}

// ---------------- fused causal attention: scores + softmax + attn_w write + PV ----------------
// 1 wave per q-row, 4 rows per block. Row scores live in LDS (8KB/row).
__global__ __launch_bounds__(256) void attn_kernel(const float* __restrict__ Qt,
                                                   const float* __restrict__ Kt,
                                                   const float* __restrict__ Vt,
                                                   float* __restrict__ attn_w,
                                                   float* __restrict__ attn_out) {
    __shared__ float srow[4][TT];
    __shared__ float qv[4][HD];
    const int bh = blockIdx.x >> 9;          // 512 row-groups per (b,h)
    const int qb = blockIdx.x & 511;
    const int wave = threadIdx.x >> 6;
    const int lane = threadIdx.x & 63;
    const int q = qb * 4 + wave;
    const float* Kb = Kt + (size_t)bh * TT * HD;
    const float* Vb = Vt + (size_t)bh * TT * HD;
    qv[wave][lane] = Qt[((size_t)bh * TT + q) * HD + lane];
    __syncthreads();

    const float scale = 0.125f;              // 1/sqrt(64)
    float mj = -1e30f, lj = 0.f;
    const float4* qp = reinterpret_cast<const float4*>(&qv[wave][0]);
    // phase 1: scores (lane j handles k = j, j+64, ...), online max/sum
    for (int k = lane; k <= q; k += 64) {
        const float4* Kr = reinterpret_cast<const float4*>(Kb + (size_t)k * HD);
        float s0 = 0.f, s1 = 0.f, s2 = 0.f, s3 = 0.f;
#pragma unroll
        for (int d = 0; d < 16; d += 4) {
            float4 k0 = Kr[d], k1 = Kr[d + 1], k2 = Kr[d + 2], k3 = Kr[d + 3];
            float4 q0 = qp[d], q1 = qp[d + 1], q2 = qp[d + 2], q3 = qp[d + 3];
            s0 = fmaf(k0.x, q0.x, fmaf(k0.y, q0.y, fmaf(k0.z, q0.z, fmaf(k0.w, q0.w, s0))));
            s1 = fmaf(k1.x, q1.x, fmaf(k1.y, q1.y, fmaf(k1.z, q1.z, fmaf(k1.w, q1.w, s1))));
            s2 = fmaf(k2.x, q2.x, fmaf(k2.y, q2.y, fmaf(k2.z, q2.z, fmaf(k2.w, q2.w, s2))));
            s3 = fmaf(k3.x, q3.x, fmaf(k3.y, q3.y, fmaf(k3.z, q3.z, fmaf(k3.w, q3.w, s3))));
        }
        const float s = (s0 + s1 + s2 + s3) * scale;
        srow[wave][k] = s;
        if (s > mj) { lj = lj * __expf(mj - s) + 1.f; mj = s; }
        else        { lj += __expf(s - mj); }
    }
    // merge (m,l) across the 64 lanes (empty lanes carry m=-1e30, l=0 -> contribute 0, no NaN)
#pragma unroll
    for (int off = 32; off; off >>= 1) {
        const float mo = __shfl_xor(mj, off, 64);
        const float lo = __shfl_xor(lj, off, 64);
        const float mn = fmaxf(mj, mo);
        lj = lj * __expf(mj - mn) + lo * __expf(mo - mn);
        mj = mn;
    }
    const float inv = 1.0f / lj;
    // phase 2: normalize, write full attn_w row (zeros above diagonal)
    float* wrow = attn_w + ((size_t)bh * TT + q) * TT;
    for (int k = lane; k < TT; k += 64) {
        float p = 0.f;
        if (k <= q) { p = __expf(srow[wave][k] - mj) * inv; srow[wave][k] = p; }
        wrow[k] = p;
    }
    // phase 3: O[d] = sum_k p[k] * V[k][d]  (lane = d, coalesced V reads)
    float o0 = 0.f, o1 = 0.f, o2 = 0.f, o3 = 0.f;
    int k = 0;
    for (; k + 3 <= q; k += 4) {
        const float p0 = srow[wave][k], p1 = srow[wave][k + 1];
        const float p2 = srow[wave][k + 2], p3 = srow[wave][k + 3];
        o0 = fmaf(p0, Vb[(size_t)k * HD + lane], o0);
        o1 = fmaf(p1, Vb[(size_t)(k + 1) * HD + lane], o1);
        o2 = fmaf(p2, Vb[(size_t)(k + 2) * HD + lane], o2);
        o3 = fmaf(p3, Vb[(size_t)(k + 3) * HD + lane], o3);
    }
    for (; k <= q; ++k) o0 = fmaf(srow[wave][k], Vb[(size_t)k * HD + lane], o0);
    const int b_ = bh >> 4, h = bh & 15;
    attn_out[((size_t)b_ * TT + q) * CC + h * HD + lane] = o0 + o1 + o2 + o3;
}

extern "C" void kernel_launch(void* const* d_in, const int* in_sizes, int n_in,
                              void* d_out, int out_size, void* d_ws, size_t ws_size,
                              hipStream_t stream) {
    (void)in_sizes; (void)n_in; (void)out_size; (void)ws_size;
    const float* x     = (const float*)d_in[0];
    const float* w_qkv = (const float*)d_in[1];
    const float* b_qkv = (const float*)d_in[2];
    const float* w_o   = (const float*)d_in[3];
    const float* b_o   = (const float*)d_in[4];

    float* out_o  = (float*)d_out;                              // [B,T,C]
    float* attn_w = out_o + (size_t)BB * TT * CC;               // [B,H,T,T]

    float* ws = (float*)d_ws;
    const size_t qkv_elems = (size_t)BB * NH * TT * HD;         // 4,194,304
    float* Q        = ws;
    float* K        = ws + qkv_elems;
    float* V        = ws + 2 * qkv_elems;
    float* attn_out = ws + 3 * qkv_elems;                       // [B,T,C]

    qkv_gemm<<<dim3(NQKV / 64, (BB * TT) / 64), 256, 0, stream>>>(x, w_qkv, b_qkv, Q, K, V);
    attn_kernel<<<dim3(BB * NH * (TT / 4)), 256, 0, stream>>>(Q, K, V, attn_w, attn_out);
    out_gemm<<<dim3(CC / 64, (BB * TT) / 64), 256, 0, stream>>>(attn_out, w_o, b_o, out_o);
}